// Round 5
// baseline (196.973 us; speedup 1.0000x reference)
//
#include <hip/hip_runtime.h>

#define BUFSZ 10000000
#define RESF 0.3f
// XLA canonicalizes x / const -> x * (1/const); 1.0f/0.3f folds to 0x40555555.
#define RINV (1.0f / 0.3f)

// ---------------------------------------------------------------------------
// Shared per-point voxel math — bit-identical to the R3/R4 passing kernels.
// ---------------------------------------------------------------------------
__device__ __forceinline__ void voxel_hash_d(float px, float py, float pz,
                                             int& hw, unsigned& dbits)
{
#pragma clang fp contract(off)
    float fx = floorf(px * RINV);
    float fy = floorf(py * RINV);
    float fz = floorf(pz * RINV);

    long long gx = (long long)fx;
    long long gy = (long long)fy;
    long long gz = (long long)fz;
    long long s = gx * 73856093LL + gy * 19349669LL + gz * 83492791LL;
    long long h = s % (long long)BUFSZ;           // trunc, sign of dividend
    hw = (int)(h < 0 ? h + BUFSZ : h);

    float cx = (fx + 0.5f) * RESF;
    float cy = (fy + 0.5f) * RESF;
    float cz = (fz + 0.5f) * RESF;
    float dx = px - cx;
    float dy = py - cy;
    float dz = pz - cz;
    float d = dx * dx + dy * dy + dz * dz;        // no fp contraction
    dbits = __float_as_uint(d);
}

// ===========================================================================
// Fused prep + min. Precondition: p8 even dwords (min-field) memset to 0xFF.
//   - plain stores ONLY to odd dwords (bufidx field)  -> no race with atomics
//   - atomicMin ONLY on even dwords (min field, pre-initialized by memset)
//   - pnt pack streamed alongside (hides under the request-limited atomics)
// ===========================================================================
__global__ __launch_bounds__(256) void fused_prep_min(
    const int* __restrict__ bufidx,
    const float* __restrict__ neural,
    const int* __restrict__ ts_upd,
    const float* __restrict__ points,
    unsigned int* __restrict__ p8w,   // uint2 table viewed as uint[2*BUFSZ]
    float4* __restrict__ pnt,
    int N, int M)
{
    int T = gridDim.x * 256;
    int g = blockIdx.x * 256 + threadIdx.x;

    for (int j = g; j < BUFSZ; j += T) {
        p8w[2LL * j + 1] = (unsigned)bufidx[j];   // idx field only (odd dword)
        if (j < M)
            pnt[j] = make_float4(neural[3 * j + 0], neural[3 * j + 1],
                                 neural[3 * j + 2], __int_as_float(ts_upd[j]));
    }

    for (int i = g; i < N; i += T) {
        float px = points[3 * i + 0];
        float py = points[3 * i + 1];
        float pz = points[3 * i + 2];
        int hw; unsigned dbits;
        voxel_hash_d(px, py, pz, hw, dbits);
        atomicMin(p8w + 2LL * hw, dbits);         // min field only (even dword)
    }
}

// ===========================================================================
// Output pass, 4 independent points per thread (stride-partitioned so each
// load instruction stays fully coalesced; 4 independent gather chains/wave
// quadruple outstanding misses).
// ===========================================================================
__global__ __launch_bounds__(256) void pass_out_A4(
    const float* __restrict__ points,
    const uint2* __restrict__ p8,
    const float4* __restrict__ pnt,
    const float* __restrict__ travel,
    const int* __restrict__ cur_ts_p,
    float* __restrict__ out,
    int N, int M, int S)              // S = ceil(N/4), partition stride
{
#pragma clang fp contract(off)
    int tid = blockIdx.x * 256 + threadIdx.x;
    if (tid >= S) return;

    float tcur = travel[cur_ts_p[0]];             // broadcast, L1-hit

    int      iv[4];
    bool     val[4];
    float    pxv[4], pyv[4], pzv[4];
    int      hwv[4];
    unsigned dbv[4];

#pragma unroll
    for (int k = 0; k < 4; ++k) {
        int i = tid + k * S;
        val[k] = (i < N);
        iv[k]  = val[k] ? i : 0;
        pxv[k] = points[3 * iv[k] + 0];
        pyv[k] = points[3 * iv[k] + 1];
        pzv[k] = points[3 * iv[k] + 2];
        voxel_hash_d(pxv[k], pyv[k], pzv[k], hwv[k], dbv[k]);
    }

    uint2 ev[4];
#pragma unroll
    for (int k = 0; k < 4; ++k) ev[k] = p8[hwv[k]];      // 4 independent 8B gathers

    int   hidxv[4], idxwv[4];
    float4 ntv[4];
#pragma unroll
    for (int k = 0; k < 4; ++k) {
        hidxv[k] = (int)ev[k].y;                          // -1 == empty
        idxwv[k] = (hidxv[k] < 0) ? (hidxv[k] + M) : hidxv[k];
    }
#pragma unroll
    for (int k = 0; k < 4; ++k) ntv[k] = pnt[idxwv[k]];   // 4 independent 16B gathers

#pragma unroll
    for (int k = 0; k < 4; ++k) {
        if (!val[k]) continue;

        bool keep = dbv[k] <= ev[k].x;

        float vx = ntv[k].x - pxv[k];
        float vy = ntv[k].y - pyv[k];
        float vz = ntv[k].z - pzv[k];
        float dist2 = vx * vx + vy * vy + vz * vz;        // no contraction

        int ts = __float_as_int(ntv[k].w);
        float dtv = tcur - travel[ts];                    // tiny table, L2-hot

        const float THR = (float)(3.0 * 0.3 * 0.3);
        bool upd = keep && ((hidxv[k] == -1) || (dist2 > THR) || (dtv > 120.0f));

        out[iv[k]]         = dist2;
        out[N + iv[k]]     = dtv;
        out[2 * N + iv[k]] = upd ? 1.0f : 0.0f;
    }
}

// ===========================================================================
// Tier C fallback (proven in R3): used only if ws is too small for Tier A.
// ===========================================================================
__global__ __launch_bounds__(256) void pass_min_C(
    const float* __restrict__ points, unsigned int* __restrict__ seg, int N)
{
    int i = blockIdx.x * 256 + threadIdx.x;
    if (i >= N) return;
    int hw; unsigned dbits;
    voxel_hash_d(points[3 * i], points[3 * i + 1], points[3 * i + 2], hw, dbits);
    atomicMin(seg + hw, dbits);
}

__global__ __launch_bounds__(256) void pass_out_C(
    const float* __restrict__ points, const float* __restrict__ neural,
    const int* __restrict__ bufidx, const float* __restrict__ travel,
    const int* __restrict__ ts_upd, const int* __restrict__ cur_ts_p,
    const unsigned int* __restrict__ seg, float* __restrict__ out, int N, int M)
{
#pragma clang fp contract(off)
    int i = blockIdx.x * 256 + threadIdx.x;
    if (i >= N) return;
    float px = points[3 * i], py = points[3 * i + 1], pz = points[3 * i + 2];
    int hw; unsigned dbits;
    voxel_hash_d(px, py, pz, hw, dbits);
    bool keep = dbits <= seg[hw];
    int hidx = bufidx[hw];
    int idxw = (hidx < 0) ? (hidx + M) : hidx;
    float vx = neural[3 * idxw] - px;
    float vy = neural[3 * idxw + 1] - py;
    float vz = neural[3 * idxw + 2] - pz;
    float dist2 = vx * vx + vy * vy + vz * vz;
    int ts = ts_upd[idxw];
    float dtv = travel[cur_ts_p[0]] - travel[ts];
    const float THR = (float)(3.0 * 0.3 * 0.3);
    bool upd = keep && ((hidx == -1) || (dist2 > THR) || (dtv > 120.0f));
    out[i] = dist2;
    out[N + i] = dtv;
    out[2 * N + i] = upd ? 1.0f : 0.0f;
}

extern "C" void kernel_launch(void* const* d_in, const int* in_sizes, int n_in,
                              void* d_out, int out_size, void* d_ws, size_t ws_size,
                              hipStream_t stream)
{
    const float* points  = (const float*)d_in[0];
    const float* neural  = (const float*)d_in[1];
    const int*   bufidx  = (const int*)d_in[2];
    const float* travel  = (const float*)d_in[3];
    const int*   ts_upd  = (const int*)d_in[4];
    const int*   cur_ts  = (const int*)d_in[5];

    int N = in_sizes[0] / 3;
    int M = in_sizes[1] / 3;

    const size_t needA = (size_t)BUFSZ * 8 + (size_t)M * 16;  // 112 MB
    if (ws_size >= needA) {
        uint2*  p8  = (uint2*)d_ws;                                // 80 MB
        float4* pnt = (float4*)((char*)d_ws + (size_t)BUFSZ * 8);  // 32 MB

        // Init min-fields (even dwords) — and idx fields, which the fused
        // kernel then overwrites with bufidx. Ordered before the kernel.
        hipMemsetAsync(p8, 0xFF, (size_t)BUFSZ * 8, stream);

        fused_prep_min<<<2048, 256, 0, stream>>>(bufidx, neural, ts_upd, points,
                                                 (unsigned int*)p8, pnt, N, M);

        int S = (N + 3) / 4;
        int oblocks = (S + 255) / 256;
        pass_out_A4<<<oblocks, 256, 0, stream>>>(points, p8, pnt, travel, cur_ts,
                                                 (float*)d_out, N, M, S);
    } else {
        unsigned int* seg = (unsigned int*)d_ws;                   // 40 MB
        hipMemsetAsync(seg, 0xFF, (size_t)BUFSZ * sizeof(unsigned int), stream);
        int pblocks = (N + 255) / 256;
        pass_min_C<<<pblocks, 256, 0, stream>>>(points, seg, N);
        pass_out_C<<<pblocks, 256, 0, stream>>>(points, neural, bufidx, travel,
                                                ts_upd, cur_ts, seg,
                                                (float*)d_out, N, M);
    }
}

// Round 6
// 183.425 us; speedup vs baseline: 1.0739x; 1.0739x over previous
//
#include <hip/hip_runtime.h>

#define BUFSZ 10000000
#define RESF 0.3f
// XLA canonicalizes x / const -> x * (1/const); 1.0f/0.3f folds to 0x40555555.
#define RINV (1.0f / 0.3f)

// ---------------------------------------------------------------------------
// Shared per-point voxel math — bit-identical to the R3/R4 passing kernels.
// ---------------------------------------------------------------------------
__device__ __forceinline__ void voxel_hash_d(float px, float py, float pz,
                                             int& hw, unsigned& dbits)
{
#pragma clang fp contract(off)
    float fx = floorf(px * RINV);
    float fy = floorf(py * RINV);
    float fz = floorf(pz * RINV);

    long long gx = (long long)fx;
    long long gy = (long long)fy;
    long long gz = (long long)fz;
    long long s = gx * 73856093LL + gy * 19349669LL + gz * 83492791LL;
    long long h = s % (long long)BUFSZ;           // trunc, sign of dividend
    hw = (int)(h < 0 ? h + BUFSZ : h);

    float cx = (fx + 0.5f) * RESF;
    float cy = (fy + 0.5f) * RESF;
    float cz = (fz + 0.5f) * RESF;
    float dx = px - cx;
    float dy = py - cy;
    float dz = pz - cz;
    float d = dx * dx + dy * dy + dz * dz;        // no fp contraction
    dbits = __float_as_uint(d);
}

// ===========================================================================
// K1: build packed hash table with FULL-LINE coalesced stores.
// p8[j] = {min=0xFFFFFFFF, idx=bufidx[j]}, two buckets per uint4 store.
// ===========================================================================
__global__ __launch_bounds__(256) void prep_p8(
    const int2* __restrict__ bufidx2,
    uint4* __restrict__ p8q,
    int nq)                            // nq = BUFSZ/2
{
    int j = blockIdx.x * 256 + threadIdx.x;
    if (j >= nq) return;
    int2 b = bufidx2[j];
    p8q[j] = make_uint4(0xFFFFFFFFu, (unsigned)b.x,
                        0xFFFFFFFFu, (unsigned)b.y);
}

// ===========================================================================
// K2: batched fire-and-forget atomics FIRST, then pnt packing streamed while
// the atomics retire. Atomics touch only even dwords of p8 (min field);
// pnt is a disjoint buffer — no races.
// ===========================================================================
__global__ __launch_bounds__(256) void min_pack(
    const float* __restrict__ points,
    const float* __restrict__ neural,
    const int* __restrict__ ts_upd,
    unsigned int* __restrict__ p8w,    // uint2 table viewed as uint[2*BUFSZ]
    float4* __restrict__ pnt,
    int N, int M, int S)               // S = ceil(N/4)
{
    int tid = blockIdx.x * 256 + threadIdx.x;
    int T   = gridDim.x * 256;

    // --- phase 1: hash atomics (4 points/thread, stride-partitioned) ---
    if (tid < S) {
        int      hwv[4];
        unsigned dbv[4];
        bool     val[4];
#pragma unroll
        for (int k = 0; k < 4; ++k) {
            int i = tid + k * S;
            val[k] = (i < N);
            int ii = val[k] ? i : 0;
            float px = points[3 * ii + 0];
            float py = points[3 * ii + 1];
            float pz = points[3 * ii + 2];
            voxel_hash_d(px, py, pz, hwv[k], dbv[k]);
        }
#pragma unroll
        for (int k = 0; k < 4; ++k)
            if (val[k])
                atomicMin(p8w + 2LL * hwv[k], dbv[k]);  // no return -> no wait
    }

    // --- phase 2: stream-pack {neural,ts} -> pnt while atomics retire ---
    for (int j = tid; j < M; j += T)
        pnt[j] = make_float4(neural[3 * j + 0], neural[3 * j + 1],
                             neural[3 * j + 2], __int_as_float(ts_upd[j]));
}

// ===========================================================================
// K3: output pass, 4 independent points per thread (coalesced per-k loads,
// 4 independent gather chains per wave). At the L2 fill-rate floor.
// ===========================================================================
__global__ __launch_bounds__(256) void pass_out_A4(
    const float* __restrict__ points,
    const uint2* __restrict__ p8,
    const float4* __restrict__ pnt,
    const float* __restrict__ travel,
    const int* __restrict__ cur_ts_p,
    float* __restrict__ out,
    int N, int M, int S)               // S = ceil(N/4)
{
#pragma clang fp contract(off)
    int tid = blockIdx.x * 256 + threadIdx.x;
    if (tid >= S) return;

    float tcur = travel[cur_ts_p[0]];  // broadcast

    int      iv[4];
    bool     val[4];
    float    pxv[4], pyv[4], pzv[4];
    int      hwv[4];
    unsigned dbv[4];

#pragma unroll
    for (int k = 0; k < 4; ++k) {
        int i = tid + k * S;
        val[k] = (i < N);
        iv[k]  = val[k] ? i : 0;
        pxv[k] = points[3 * iv[k] + 0];
        pyv[k] = points[3 * iv[k] + 1];
        pzv[k] = points[3 * iv[k] + 2];
        voxel_hash_d(pxv[k], pyv[k], pzv[k], hwv[k], dbv[k]);
    }

    uint2 ev[4];
#pragma unroll
    for (int k = 0; k < 4; ++k) ev[k] = p8[hwv[k]];      // 4 independent 8B gathers

    int hidxv[4], idxwv[4];
    float4 ntv[4];
#pragma unroll
    for (int k = 0; k < 4; ++k) {
        hidxv[k] = (int)ev[k].y;                          // -1 == empty
        idxwv[k] = (hidxv[k] < 0) ? (hidxv[k] + M) : hidxv[k];
    }
#pragma unroll
    for (int k = 0; k < 4; ++k) ntv[k] = pnt[idxwv[k]];   // 4 independent 16B gathers

#pragma unroll
    for (int k = 0; k < 4; ++k) {
        if (!val[k]) continue;

        bool keep = dbv[k] <= ev[k].x;

        float vx = ntv[k].x - pxv[k];
        float vy = ntv[k].y - pyv[k];
        float vz = ntv[k].z - pzv[k];
        float dist2 = vx * vx + vy * vy + vz * vz;        // no contraction

        int ts = __float_as_int(ntv[k].w);
        float dtv = tcur - travel[ts];

        const float THR = (float)(3.0 * 0.3 * 0.3);
        bool upd = keep && ((hidxv[k] == -1) || (dist2 > THR) || (dtv > 120.0f));

        out[iv[k]]         = dist2;
        out[N + iv[k]]     = dtv;
        out[2 * N + iv[k]] = upd ? 1.0f : 0.0f;
    }
}

// ===========================================================================
// Tier C fallback (proven in R3): used only if ws is too small for Tier A.
// ===========================================================================
__global__ __launch_bounds__(256) void pass_min_C(
    const float* __restrict__ points, unsigned int* __restrict__ seg, int N)
{
    int i = blockIdx.x * 256 + threadIdx.x;
    if (i >= N) return;
    int hw; unsigned dbits;
    voxel_hash_d(points[3 * i], points[3 * i + 1], points[3 * i + 2], hw, dbits);
    atomicMin(seg + hw, dbits);
}

__global__ __launch_bounds__(256) void pass_out_C(
    const float* __restrict__ points, const float* __restrict__ neural,
    const int* __restrict__ bufidx, const float* __restrict__ travel,
    const int* __restrict__ ts_upd, const int* __restrict__ cur_ts_p,
    const unsigned int* __restrict__ seg, float* __restrict__ out, int N, int M)
{
#pragma clang fp contract(off)
    int i = blockIdx.x * 256 + threadIdx.x;
    if (i >= N) return;
    float px = points[3 * i], py = points[3 * i + 1], pz = points[3 * i + 2];
    int hw; unsigned dbits;
    voxel_hash_d(px, py, pz, hw, dbits);
    bool keep = dbits <= seg[hw];
    int hidx = bufidx[hw];
    int idxw = (hidx < 0) ? (hidx + M) : hidx;
    float vx = neural[3 * idxw] - px;
    float vy = neural[3 * idxw + 1] - py;
    float vz = neural[3 * idxw + 2] - pz;
    float dist2 = vx * vx + vy * vy + vz * vz;
    int ts = ts_upd[idxw];
    float dtv = travel[cur_ts_p[0]] - travel[ts];
    const float THR = (float)(3.0 * 0.3 * 0.3);
    bool upd = keep && ((hidx == -1) || (dist2 > THR) || (dtv > 120.0f));
    out[i] = dist2;
    out[N + i] = dtv;
    out[2 * N + i] = upd ? 1.0f : 0.0f;
}

extern "C" void kernel_launch(void* const* d_in, const int* in_sizes, int n_in,
                              void* d_out, int out_size, void* d_ws, size_t ws_size,
                              hipStream_t stream)
{
    const float* points  = (const float*)d_in[0];
    const float* neural  = (const float*)d_in[1];
    const int*   bufidx  = (const int*)d_in[2];
    const float* travel  = (const float*)d_in[3];
    const int*   ts_upd  = (const int*)d_in[4];
    const int*   cur_ts  = (const int*)d_in[5];

    int N = in_sizes[0] / 3;
    int M = in_sizes[1] / 3;

    const size_t needA = (size_t)BUFSZ * 8 + (size_t)M * 16;  // 112 MB
    if (ws_size >= needA) {
        uint2*  p8  = (uint2*)d_ws;                                // 80 MB
        float4* pnt = (float4*)((char*)d_ws + (size_t)BUFSZ * 8);  // 32 MB

        int nq = BUFSZ / 2;
        prep_p8<<<(nq + 255) / 256, 256, 0, stream>>>(
            (const int2*)bufidx, (uint4*)p8, nq);

        int S = (N + 3) / 4;
        int blocks = (S + 255) / 256;
        min_pack<<<blocks, 256, 0, stream>>>(points, neural, ts_upd,
                                             (unsigned int*)p8, pnt, N, M, S);

        pass_out_A4<<<blocks, 256, 0, stream>>>(points, p8, pnt, travel, cur_ts,
                                                (float*)d_out, N, M, S);
    } else {
        unsigned int* seg = (unsigned int*)d_ws;                   // 40 MB
        hipMemsetAsync(seg, 0xFF, (size_t)BUFSZ * sizeof(unsigned int), stream);
        int pblocks = (N + 255) / 256;
        pass_min_C<<<pblocks, 256, 0, stream>>>(points, seg, N);
        pass_out_C<<<pblocks, 256, 0, stream>>>(points, neural, bufidx, travel,
                                                ts_upd, cur_ts, seg,
                                                (float*)d_out, N, M);
    }
}

// Round 7
// 180.317 us; speedup vs baseline: 1.0924x; 1.0172x over previous
//
#include <hip/hip_runtime.h>

#define BUFSZ 10000000
#define RESF 0.3f
// XLA canonicalizes x / const -> x * (1/const); 1.0f/0.3f folds to 0x40555555.
#define RINV (1.0f / 0.3f)

// ---- binning geometry -----------------------------------------------------
#define BIN_SHIFT   14
#define BKT_PER_BIN 16384                    // buckets per bin (64 KB LDS table)
#define NBINS       611                      // ceil(10M / 16384)
#define BIN_CAP     6016                     // slots/bin (mean 3273, e^-900 overflow)
#define OVF_CAP     4000

// ---- ws layout (fits the proven 112 MB = 80M p8 + 32M pnt) ----------------
// [0, 80M)          p8   uint2[10M]  {min_bits, bufidx}
// [80M, 109.41M)    bins_e u64[NBINS*BIN_CAP]   (later overwritten by pnt)
// [110.00M, +4KB)   ctl  u32[NBINS] counts + [NBINS]=ovf count
// [110.004M, +32KB) ovf  u64[OVF_CAP]           (read before pnt clobbers it)
// [80M, 112M)       pnt  float4[2M]  (written AFTER bins/ctl/ovf consumed)
#define BINS_OFF 80000000ull
#define CTL_OFF  110000000ull
#define OVF_OFF  (CTL_OFF + 4096ull)

// ---------------------------------------------------------------------------
// Shared per-point voxel math — bit-identical to the R3..R6 passing kernels.
// ---------------------------------------------------------------------------
__device__ __forceinline__ void voxel_hash_d(float px, float py, float pz,
                                             int& hw, unsigned& dbits)
{
#pragma clang fp contract(off)
    float fx = floorf(px * RINV);
    float fy = floorf(py * RINV);
    float fz = floorf(pz * RINV);

    long long gx = (long long)fx;
    long long gy = (long long)fy;
    long long gz = (long long)fz;
    long long s = gx * 73856093LL + gy * 19349669LL + gz * 83492791LL;
    long long h = s % (long long)BUFSZ;           // trunc, sign of dividend
    hw = (int)(h < 0 ? h + BUFSZ : h);

    float cx = (fx + 0.5f) * RESF;
    float cy = (fy + 0.5f) * RESF;
    float cz = (fz + 0.5f) * RESF;
    float dx = px - cx;
    float dy = py - cy;
    float dz = pz - cz;
    float d = dx * dx + dy * dy + dz * dz;        // no fp contraction
    dbits = __float_as_uint(d);
}

// ===========================================================================
// K1: multisplit binning. Block handles 4096 points; LDS histogram ->
// one global atomicAdd per (block,bin) -> clustered 8B entry scatter.
// Entries with dbits >= 2^30 (impossible for this input, but exactness-safe)
// and bin-capacity overflow go to the ovf buffer (global atomicMin later).
// ===========================================================================
__global__ __launch_bounds__(256) void bin_points(
    const float* __restrict__ points,
    unsigned long long* __restrict__ bins_e,
    unsigned int* __restrict__ ctl,
    unsigned long long* __restrict__ ovf,
    int N)
{
    __shared__ unsigned int cnt[NBINS];
    int t = threadIdx.x;
    for (int b = t; b < NBINS; b += 256) cnt[b] = 0;
    __syncthreads();

    int base = blockIdx.x * (256 * 16);
    unsigned hwv[16];
    unsigned dbv[16];

#pragma unroll
    for (int k = 0; k < 16; ++k) {
        int i = base + t + k * 256;
        hwv[k] = 0xFFFFFFFFu;                      // sentinel: invalid (hw < 10M)
        dbv[k] = 0;
        if (i < N) {
            int hw; unsigned db;
            voxel_hash_d(points[3 * i], points[3 * i + 1], points[3 * i + 2],
                         hw, db);
            hwv[k] = (unsigned)hw;
            dbv[k] = db;
            if (db <= 0x3FFFFFFFu)
                atomicAdd(&cnt[hw >> BIN_SHIFT], 1u);
        }
    }
    __syncthreads();

    // reserve global ranges; cnt[b] becomes the block's running global cursor
    for (int b = t; b < NBINS; b += 256) {
        unsigned c = cnt[b];
        cnt[b] = c ? atomicAdd(&ctl[b], c) : 0u;
    }
    __syncthreads();

#pragma unroll
    for (int k = 0; k < 16; ++k) {
        if (hwv[k] == 0xFFFFFFFFu) continue;
        unsigned hw = hwv[k], db = dbv[k];
        if (db <= 0x3FFFFFFFu) {
            unsigned bin = hw >> BIN_SHIFT;
            unsigned idx = atomicAdd(&cnt[bin], 1u);
            if (idx < BIN_CAP) {
                bins_e[(size_t)bin * BIN_CAP + idx] =
                    ((unsigned long long)db << BIN_SHIFT)
                    | (hw & (BKT_PER_BIN - 1));
                continue;
            }
        }
        unsigned o = atomicAdd(&ctl[NBINS], 1u);
        if (o < OVF_CAP)
            ovf[o] = ((unsigned long long)db << 32) | hw;
    }
}

// ===========================================================================
// K2: per-bin LDS segment-min + sequential writeback fused with bufidx pack.
// Replaces 2M random global atomics with LDS atomics + pure streaming.
// ===========================================================================
__global__ __launch_bounds__(256) void min_bins(
    const unsigned long long* __restrict__ bins_e,
    const unsigned int* __restrict__ ctl,
    const int* __restrict__ bufidx,
    uint2* __restrict__ p8)
{
    __shared__ unsigned int tbl[BKT_PER_BIN];      // 64 KB
    int t = threadIdx.x;
    int b = blockIdx.x;

    uint4* t4 = (uint4*)tbl;
    for (int l = t; l < BKT_PER_BIN / 4; l += 256)
        t4[l] = make_uint4(0xFFFFFFFFu, 0xFFFFFFFFu, 0xFFFFFFFFu, 0xFFFFFFFFu);
    __syncthreads();

    unsigned c = ctl[b];
    if (c > BIN_CAP) c = BIN_CAP;                  // excess went to ovf
    const unsigned long long* e = bins_e + (size_t)b * BIN_CAP;
    for (unsigned j = t; j < c; j += 256) {
        unsigned long long v = e[j];
        atomicMin(&tbl[(unsigned)(v & (BKT_PER_BIN - 1))],
                  (unsigned)(v >> BIN_SHIFT));
    }
    __syncthreads();

    long long gbase = (long long)b * BKT_PER_BIN;
    for (int l = t; l < BKT_PER_BIN; l += 256) {
        long long g = gbase + l;
        if (g < (long long)BUFSZ)
            p8[g] = make_uint2(tbl[l], (unsigned)bufidx[g]);
    }
}

// ===========================================================================
// K3: drain overflow entries (statistically empty) with exact global atomics.
// Must run after min_bins (plain writeback) and before pack_pnt (clobbers ovf).
// ===========================================================================
__global__ __launch_bounds__(256) void fix_ovf(
    const unsigned int* __restrict__ ctl,
    const unsigned long long* __restrict__ ovf,
    unsigned int* __restrict__ p8w)
{
    unsigned c = ctl[NBINS];
    if (c > OVF_CAP) c = OVF_CAP;
    for (unsigned e = threadIdx.x; e < c; e += 256) {
        unsigned long long v = ovf[e];
        atomicMin(p8w + 2ull * (unsigned)(v & 0xFFFFFFFFu), (unsigned)(v >> 32));
    }
}

// ===========================================================================
// K4: stream-pack {neural, ts} -> pnt (overwrites the consumed bins region).
// ===========================================================================
__global__ __launch_bounds__(256) void pack_pnt(
    const float* __restrict__ neural,
    const int* __restrict__ ts_upd,
    float4* __restrict__ pnt, int M)
{
    int T = gridDim.x * 256;
    for (int j = blockIdx.x * 256 + threadIdx.x; j < M; j += T)
        pnt[j] = make_float4(neural[3 * j], neural[3 * j + 1],
                             neural[3 * j + 2], __int_as_float(ts_upd[j]));
}

// ===========================================================================
// K5: output pass, 4 independent points per thread (at the random-fill floor).
// ===========================================================================
__global__ __launch_bounds__(256) void pass_out_A4(
    const float* __restrict__ points,
    const uint2* __restrict__ p8,
    const float4* __restrict__ pnt,
    const float* __restrict__ travel,
    const int* __restrict__ cur_ts_p,
    float* __restrict__ out,
    int N, int M, int S)               // S = ceil(N/4)
{
#pragma clang fp contract(off)
    int tid = blockIdx.x * 256 + threadIdx.x;
    if (tid >= S) return;

    float tcur = travel[cur_ts_p[0]];

    int      iv[4];
    bool     val[4];
    float    pxv[4], pyv[4], pzv[4];
    int      hwv[4];
    unsigned dbv[4];

#pragma unroll
    for (int k = 0; k < 4; ++k) {
        int i = tid + k * S;
        val[k] = (i < N);
        iv[k]  = val[k] ? i : 0;
        pxv[k] = points[3 * iv[k] + 0];
        pyv[k] = points[3 * iv[k] + 1];
        pzv[k] = points[3 * iv[k] + 2];
        voxel_hash_d(pxv[k], pyv[k], pzv[k], hwv[k], dbv[k]);
    }

    uint2 ev[4];
#pragma unroll
    for (int k = 0; k < 4; ++k) ev[k] = p8[hwv[k]];

    int hidxv[4], idxwv[4];
    float4 ntv[4];
#pragma unroll
    for (int k = 0; k < 4; ++k) {
        hidxv[k] = (int)ev[k].y;
        idxwv[k] = (hidxv[k] < 0) ? (hidxv[k] + M) : hidxv[k];
    }
#pragma unroll
    for (int k = 0; k < 4; ++k) ntv[k] = pnt[idxwv[k]];

#pragma unroll
    for (int k = 0; k < 4; ++k) {
        if (!val[k]) continue;

        bool keep = dbv[k] <= ev[k].x;

        float vx = ntv[k].x - pxv[k];
        float vy = ntv[k].y - pyv[k];
        float vz = ntv[k].z - pzv[k];
        float dist2 = vx * vx + vy * vy + vz * vz;

        int ts = __float_as_int(ntv[k].w);
        float dtv = tcur - travel[ts];

        const float THR = (float)(3.0 * 0.3 * 0.3);
        bool upd = keep && ((hidxv[k] == -1) || (dist2 > THR) || (dtv > 120.0f));

        out[iv[k]]         = dist2;
        out[N + iv[k]]     = dtv;
        out[2 * N + iv[k]] = upd ? 1.0f : 0.0f;
    }
}

// ===========================================================================
// Tier C fallback (proven in R3): used only if ws is too small for Tier A.
// ===========================================================================
__global__ __launch_bounds__(256) void pass_min_C(
    const float* __restrict__ points, unsigned int* __restrict__ seg, int N)
{
    int i = blockIdx.x * 256 + threadIdx.x;
    if (i >= N) return;
    int hw; unsigned dbits;
    voxel_hash_d(points[3 * i], points[3 * i + 1], points[3 * i + 2], hw, dbits);
    atomicMin(seg + hw, dbits);
}

__global__ __launch_bounds__(256) void pass_out_C(
    const float* __restrict__ points, const float* __restrict__ neural,
    const int* __restrict__ bufidx, const float* __restrict__ travel,
    const int* __restrict__ ts_upd, const int* __restrict__ cur_ts_p,
    const unsigned int* __restrict__ seg, float* __restrict__ out, int N, int M)
{
#pragma clang fp contract(off)
    int i = blockIdx.x * 256 + threadIdx.x;
    if (i >= N) return;
    float px = points[3 * i], py = points[3 * i + 1], pz = points[3 * i + 2];
    int hw; unsigned dbits;
    voxel_hash_d(px, py, pz, hw, dbits);
    bool keep = dbits <= seg[hw];
    int hidx = bufidx[hw];
    int idxw = (hidx < 0) ? (hidx + M) : hidx;
    float vx = neural[3 * idxw] - px;
    float vy = neural[3 * idxw + 1] - py;
    float vz = neural[3 * idxw + 2] - pz;
    float dist2 = vx * vx + vy * vy + vz * vz;
    int ts = ts_upd[idxw];
    float dtv = travel[cur_ts_p[0]] - travel[ts];
    const float THR = (float)(3.0 * 0.3 * 0.3);
    bool upd = keep && ((hidx == -1) || (dist2 > THR) || (dtv > 120.0f));
    out[i] = dist2;
    out[N + i] = dtv;
    out[2 * N + i] = upd ? 1.0f : 0.0f;
}

extern "C" void kernel_launch(void* const* d_in, const int* in_sizes, int n_in,
                              void* d_out, int out_size, void* d_ws, size_t ws_size,
                              hipStream_t stream)
{
    const float* points  = (const float*)d_in[0];
    const float* neural  = (const float*)d_in[1];
    const int*   bufidx  = (const int*)d_in[2];
    const float* travel  = (const float*)d_in[3];
    const int*   ts_upd  = (const int*)d_in[4];
    const int*   cur_ts  = (const int*)d_in[5];

    int N = in_sizes[0] / 3;
    int M = in_sizes[1] / 3;

    const size_t needA = (size_t)BUFSZ * 8 + (size_t)M * 16;  // 112 MB (proven)
    if (ws_size >= needA && N <= 2000000) {
        char* ws = (char*)d_ws;
        uint2*              p8     = (uint2*)ws;
        unsigned long long* bins_e = (unsigned long long*)(ws + BINS_OFF);
        unsigned int*       ctl    = (unsigned int*)(ws + CTL_OFF);
        unsigned long long* ovf    = (unsigned long long*)(ws + OVF_OFF);
        float4*             pnt    = (float4*)(ws + BINS_OFF);  // reuse after K_fix

        hipMemsetAsync(ctl, 0, 4096, stream);

        int bblocks = (N + 4095) / 4096;
        bin_points<<<bblocks, 256, 0, stream>>>(points, bins_e, ctl, ovf, N);
        min_bins<<<NBINS, 256, 0, stream>>>(bins_e, ctl, bufidx, p8);
        fix_ovf<<<1, 256, 0, stream>>>(ctl, ovf, (unsigned int*)p8);
        pack_pnt<<<2048, 256, 0, stream>>>(neural, ts_upd, pnt, M);

        int S = (N + 3) / 4;
        int oblocks = (S + 255) / 256;
        pass_out_A4<<<oblocks, 256, 0, stream>>>(points, p8, pnt, travel, cur_ts,
                                                 (float*)d_out, N, M, S);
    } else {
        unsigned int* seg = (unsigned int*)d_ws;               // 40 MB
        hipMemsetAsync(seg, 0xFF, (size_t)BUFSZ * sizeof(unsigned int), stream);
        int pblocks = (N + 255) / 256;
        pass_min_C<<<pblocks, 256, 0, stream>>>(points, seg, N);
        pass_out_C<<<pblocks, 256, 0, stream>>>(points, neural, bufidx, travel,
                                                ts_upd, cur_ts, seg,
                                                (float*)d_out, N, M);
    }
}

// Round 8
// 157.164 us; speedup vs baseline: 1.2533x; 1.1473x over previous
//
#include <hip/hip_runtime.h>

#define BUFSZ 10000000
#define RESF 0.3f
// XLA canonicalizes x / const -> x * (1/const); 1.0f/0.3f folds to 0x40555555.
#define RINV (1.0f / 0.3f)

// ---- binning geometry -----------------------------------------------------
#define BIN_SHIFT   13
#define BKT_PER_BIN 8192                     // buckets per bin (32 KB LDS table)
#define NBINS       1221                     // ceil(10M / 8192)
#define BIN_CAP     2048                     // slots/bin (mean 1638, +10 sigma)
#define OVF_CAP     4000

// ---- ws layout (fits the proven 112 MB = 80M p8 + 32M pnt) ----------------
// [0, 80M)            p8     uint2[10M]  {min_bits, bufidx}
// [80M, ~100.0M)      bins_e u64[NBINS*BIN_CAP]    (later overwritten by pnt)
// [110.000M, +8KB)    ctl    u32[NBINS] counts + [NBINS]=ovf count
// [110.008M, +32KB)   ovf    u64[OVF_CAP]          (read before pnt clobbers)
// [80M, 112M)         pnt    float4[2M]  (written AFTER bins/ctl/ovf consumed)
#define BINS_OFF 80000000ull
#define CTL_OFF  110000000ull
#define OVF_OFF  (CTL_OFF + 8192ull)

// ---------------------------------------------------------------------------
// Shared per-point voxel math — bit-identical to the R3..R7 passing kernels.
// ---------------------------------------------------------------------------
__device__ __forceinline__ void voxel_hash_d(float px, float py, float pz,
                                             int& hw, unsigned& dbits)
{
#pragma clang fp contract(off)
    float fx = floorf(px * RINV);
    float fy = floorf(py * RINV);
    float fz = floorf(pz * RINV);

    long long gx = (long long)fx;
    long long gy = (long long)fy;
    long long gz = (long long)fz;
    long long s = gx * 73856093LL + gy * 19349669LL + gz * 83492791LL;
    long long h = s % (long long)BUFSZ;           // trunc, sign of dividend
    hw = (int)(h < 0 ? h + BUFSZ : h);

    float cx = (fx + 0.5f) * RESF;
    float cy = (fy + 0.5f) * RESF;
    float cz = (fz + 0.5f) * RESF;
    float dx = px - cx;
    float dy = py - cy;
    float dz = pz - cz;
    float d = dx * dx + dy * dy + dz * dz;        // no fp contraction
    dbits = __float_as_uint(d);
}

// ===========================================================================
// K1: multisplit binning. Block handles 4096 points; LDS histogram ->
// one global atomicAdd per (block,bin) -> clustered 8B entry scatter.
// dbits >= 2^30 (impossible here, but exactness-safe) and bin-capacity
// overflow go to the ovf buffer (drained by exact global atomics in K3).
// ===========================================================================
__global__ __launch_bounds__(256) void bin_points(
    const float* __restrict__ points,
    unsigned long long* __restrict__ bins_e,
    unsigned int* __restrict__ ctl,
    unsigned long long* __restrict__ ovf,
    int N)
{
    __shared__ unsigned int cnt[NBINS];
    int t = threadIdx.x;
    for (int b = t; b < NBINS; b += 256) cnt[b] = 0;
    __syncthreads();

    int base = blockIdx.x * (256 * 16);
    unsigned hwv[16];
    unsigned dbv[16];

#pragma unroll
    for (int k = 0; k < 16; ++k) {
        int i = base + t + k * 256;
        hwv[k] = 0xFFFFFFFFu;                      // sentinel: invalid
        dbv[k] = 0;
        if (i < N) {
            int hw; unsigned db;
            voxel_hash_d(points[3 * i], points[3 * i + 1], points[3 * i + 2],
                         hw, db);
            hwv[k] = (unsigned)hw;
            dbv[k] = db;
            if (db <= 0x3FFFFFFFu)
                atomicAdd(&cnt[hw >> BIN_SHIFT], 1u);
        }
    }
    __syncthreads();

    // reserve global ranges; cnt[b] becomes the block's running global cursor
    for (int b = t; b < NBINS; b += 256) {
        unsigned c = cnt[b];
        cnt[b] = c ? atomicAdd(&ctl[b], c) : 0u;
    }
    __syncthreads();

#pragma unroll
    for (int k = 0; k < 16; ++k) {
        if (hwv[k] == 0xFFFFFFFFu) continue;
        unsigned hw = hwv[k], db = dbv[k];
        if (db <= 0x3FFFFFFFu) {
            unsigned bin = hw >> BIN_SHIFT;
            unsigned idx = atomicAdd(&cnt[bin], 1u);
            if (idx < BIN_CAP) {
                bins_e[(size_t)bin * BIN_CAP + idx] =
                    ((unsigned long long)db << BIN_SHIFT)
                    | (hw & (BKT_PER_BIN - 1));
                continue;
            }
        }
        unsigned o = atomicAdd(&ctl[NBINS], 1u);
        if (o < OVF_CAP)
            ovf[o] = ((unsigned long long)db << 32) | hw;
    }
}

// ===========================================================================
// K2: per-bin LDS segment-min + sequential uint4 writeback fused with the
// bufidx pack. 32 KB LDS -> 5 blocks/CU (~62% occupancy), 1221 blocks =
// one full concurrent wave across 256 CUs.
// ===========================================================================
__global__ __launch_bounds__(256) void min_bins(
    const unsigned long long* __restrict__ bins_e,
    const unsigned int* __restrict__ ctl,
    const int2* __restrict__ bufidx2,
    uint4* __restrict__ p8q)           // p8 viewed as uint4[5M] (2 buckets each)
{
    __shared__ unsigned int tbl[BKT_PER_BIN];      // 32 KB
    int t = threadIdx.x;
    int b = blockIdx.x;

    uint4* t4 = (uint4*)tbl;
    for (int l = t; l < BKT_PER_BIN / 4; l += 256)
        t4[l] = make_uint4(0xFFFFFFFFu, 0xFFFFFFFFu, 0xFFFFFFFFu, 0xFFFFFFFFu);
    __syncthreads();

    unsigned c = ctl[b];
    if (c > BIN_CAP) c = BIN_CAP;                  // excess went to ovf
    const unsigned long long* e = bins_e + (size_t)b * BIN_CAP;
    for (unsigned j = t; j < c; j += 256) {
        unsigned long long v = e[j];
        atomicMin(&tbl[(unsigned)(v & (BKT_PER_BIN - 1))],
                  (unsigned)(v >> BIN_SHIFT));
    }
    __syncthreads();

    // writeback: pair of buckets per uint4 store, bufidx read as int2
    long long pbase = (long long)b * (BKT_PER_BIN / 2);   // pair index base
    for (int l = t; l < BKT_PER_BIN / 2; l += 256) {
        long long pp = pbase + l;                  // global pair index
        long long g = 2 * pp;                      // global bucket index
        if (g + 1 < (long long)BUFSZ) {
            int2 bi = bufidx2[pp];
            p8q[pp] = make_uint4(tbl[2 * l], (unsigned)bi.x,
                                 tbl[2 * l + 1], (unsigned)bi.y);
        }
    }
}

// ===========================================================================
// K3: drain overflow entries (statistically empty) with exact global atomics.
// Runs after min_bins (plain writeback) and before pack_pnt (clobbers ovf).
// ===========================================================================
__global__ __launch_bounds__(256) void fix_ovf(
    const unsigned int* __restrict__ ctl,
    const unsigned long long* __restrict__ ovf,
    unsigned int* __restrict__ p8w)
{
    unsigned c = ctl[NBINS];
    if (c > OVF_CAP) c = OVF_CAP;
    for (unsigned e = threadIdx.x; e < c; e += 256) {
        unsigned long long v = ovf[e];
        atomicMin(p8w + 2ull * (unsigned)(v & 0xFFFFFFFFu), (unsigned)(v >> 32));
    }
}

// ===========================================================================
// K4: stream-pack {neural, ts} -> pnt (overwrites the consumed bins region).
// ===========================================================================
__global__ __launch_bounds__(256) void pack_pnt(
    const float* __restrict__ neural,
    const int* __restrict__ ts_upd,
    float4* __restrict__ pnt, int M)
{
    int T = gridDim.x * 256;
    for (int j = blockIdx.x * 256 + threadIdx.x; j < M; j += T)
        pnt[j] = make_float4(neural[3 * j], neural[3 * j + 1],
                             neural[3 * j + 2], __int_as_float(ts_upd[j]));
}

// ===========================================================================
// K5: output pass, 4 independent points per thread (at the random-fill floor).
// ===========================================================================
__global__ __launch_bounds__(256) void pass_out_A4(
    const float* __restrict__ points,
    const uint2* __restrict__ p8,
    const float4* __restrict__ pnt,
    const float* __restrict__ travel,
    const int* __restrict__ cur_ts_p,
    float* __restrict__ out,
    int N, int M, int S)               // S = ceil(N/4)
{
#pragma clang fp contract(off)
    int tid = blockIdx.x * 256 + threadIdx.x;
    if (tid >= S) return;

    float tcur = travel[cur_ts_p[0]];

    int      iv[4];
    bool     val[4];
    float    pxv[4], pyv[4], pzv[4];
    int      hwv[4];
    unsigned dbv[4];

#pragma unroll
    for (int k = 0; k < 4; ++k) {
        int i = tid + k * S;
        val[k] = (i < N);
        iv[k]  = val[k] ? i : 0;
        pxv[k] = points[3 * iv[k] + 0];
        pyv[k] = points[3 * iv[k] + 1];
        pzv[k] = points[3 * iv[k] + 2];
        voxel_hash_d(pxv[k], pyv[k], pzv[k], hwv[k], dbv[k]);
    }

    uint2 ev[4];
#pragma unroll
    for (int k = 0; k < 4; ++k) ev[k] = p8[hwv[k]];

    int hidxv[4], idxwv[4];
    float4 ntv[4];
#pragma unroll
    for (int k = 0; k < 4; ++k) {
        hidxv[k] = (int)ev[k].y;
        idxwv[k] = (hidxv[k] < 0) ? (hidxv[k] + M) : hidxv[k];
    }
#pragma unroll
    for (int k = 0; k < 4; ++k) ntv[k] = pnt[idxwv[k]];

#pragma unroll
    for (int k = 0; k < 4; ++k) {
        if (!val[k]) continue;

        bool keep = dbv[k] <= ev[k].x;

        float vx = ntv[k].x - pxv[k];
        float vy = ntv[k].y - pyv[k];
        float vz = ntv[k].z - pzv[k];
        float dist2 = vx * vx + vy * vy + vz * vz;

        int ts = __float_as_int(ntv[k].w);
        float dtv = tcur - travel[ts];

        const float THR = (float)(3.0 * 0.3 * 0.3);
        bool upd = keep && ((hidxv[k] == -1) || (dist2 > THR) || (dtv > 120.0f));

        out[iv[k]]         = dist2;
        out[N + iv[k]]     = dtv;
        out[2 * N + iv[k]] = upd ? 1.0f : 0.0f;
    }
}

// ===========================================================================
// Tier C fallback (proven in R3): used only if ws is too small for Tier A.
// ===========================================================================
__global__ __launch_bounds__(256) void pass_min_C(
    const float* __restrict__ points, unsigned int* __restrict__ seg, int N)
{
    int i = blockIdx.x * 256 + threadIdx.x;
    if (i >= N) return;
    int hw; unsigned dbits;
    voxel_hash_d(points[3 * i], points[3 * i + 1], points[3 * i + 2], hw, dbits);
    atomicMin(seg + hw, dbits);
}

__global__ __launch_bounds__(256) void pass_out_C(
    const float* __restrict__ points, const float* __restrict__ neural,
    const int* __restrict__ bufidx, const float* __restrict__ travel,
    const int* __restrict__ ts_upd, const int* __restrict__ cur_ts_p,
    const unsigned int* __restrict__ seg, float* __restrict__ out, int N, int M)
{
#pragma clang fp contract(off)
    int i = blockIdx.x * 256 + threadIdx.x;
    if (i >= N) return;
    float px = points[3 * i], py = points[3 * i + 1], pz = points[3 * i + 2];
    int hw; unsigned dbits;
    voxel_hash_d(px, py, pz, hw, dbits);
    bool keep = dbits <= seg[hw];
    int hidx = bufidx[hw];
    int idxw = (hidx < 0) ? (hidx + M) : hidx;
    float vx = neural[3 * idxw] - px;
    float vy = neural[3 * idxw + 1] - py;
    float vz = neural[3 * idxw + 2] - pz;
    float dist2 = vx * vx + vy * vy + vz * vz;
    int ts = ts_upd[idxw];
    float dtv = travel[cur_ts_p[0]] - travel[ts];
    const float THR = (float)(3.0 * 0.3 * 0.3);
    bool upd = keep && ((hidx == -1) || (dist2 > THR) || (dtv > 120.0f));
    out[i] = dist2;
    out[N + i] = dtv;
    out[2 * N + i] = upd ? 1.0f : 0.0f;
}

extern "C" void kernel_launch(void* const* d_in, const int* in_sizes, int n_in,
                              void* d_out, int out_size, void* d_ws, size_t ws_size,
                              hipStream_t stream)
{
    const float* points  = (const float*)d_in[0];
    const float* neural  = (const float*)d_in[1];
    const int*   bufidx  = (const int*)d_in[2];
    const float* travel  = (const float*)d_in[3];
    const int*   ts_upd  = (const int*)d_in[4];
    const int*   cur_ts  = (const int*)d_in[5];

    int N = in_sizes[0] / 3;
    int M = in_sizes[1] / 3;

    const size_t needA = (size_t)BUFSZ * 8 + (size_t)M * 16;  // 112 MB (proven)
    if (ws_size >= needA && N <= 2000000) {
        char* ws = (char*)d_ws;
        uint2*              p8     = (uint2*)ws;
        unsigned long long* bins_e = (unsigned long long*)(ws + BINS_OFF);
        unsigned int*       ctl    = (unsigned int*)(ws + CTL_OFF);
        unsigned long long* ovf    = (unsigned long long*)(ws + OVF_OFF);
        float4*             pnt    = (float4*)(ws + BINS_OFF);  // reuse after K3

        hipMemsetAsync(ctl, 0, 8192, stream);

        int bblocks = (N + 4095) / 4096;
        bin_points<<<bblocks, 256, 0, stream>>>(points, bins_e, ctl, ovf, N);
        min_bins<<<NBINS, 256, 0, stream>>>(bins_e, ctl, (const int2*)bufidx,
                                            (uint4*)p8);
        fix_ovf<<<1, 256, 0, stream>>>(ctl, ovf, (unsigned int*)p8);
        pack_pnt<<<2048, 256, 0, stream>>>(neural, ts_upd, pnt, M);

        int S = (N + 3) / 4;
        int oblocks = (S + 255) / 256;
        pass_out_A4<<<oblocks, 256, 0, stream>>>(points, p8, pnt, travel, cur_ts,
                                                 (float*)d_out, N, M, S);
    } else {
        unsigned int* seg = (unsigned int*)d_ws;               // 40 MB
        hipMemsetAsync(seg, 0xFF, (size_t)BUFSZ * sizeof(unsigned int), stream);
        int pblocks = (N + 255) / 256;
        pass_min_C<<<pblocks, 256, 0, stream>>>(points, seg, N);
        pass_out_C<<<pblocks, 256, 0, stream>>>(points, neural, bufidx, travel,
                                                ts_upd, cur_ts, seg,
                                                (float*)d_out, N, M);
    }
}